// Round 1
// baseline (5033.727 us; speedup 1.0000x reference)
//
#include <hip/hip_runtime.h>
#include <hip/hip_bf16.h>

// LSTM: N=640 seqs (B*Q fused), T=100, D=H=512. Inputs fp32; d_out fp32.
// R7 on top of R6 (passing, 1802 us):
//   ONE persistent kernel for all 100 timesteps (was 100 launches):
//   - per-(sb,t) 32-block device-scope barrier (only same-seq-group blocks
//     exchange h); release atomicAdd after epilogue, relaxed spin + fence.
//     Deadlock-safe WITHOUT cooperative launch: __launch_bounds__(256,2) +
//     33.8KB LDS -> >=2 blocks/CU -> all 320 blocks co-resident by capacity.
//   - weight slice (64 rows x 1024 K) lives in REGISTERS, loaded once:
//     32 x short8 = 128 VGPR/lane; no per-step weight traffic at all.
//   - c state in 4 fp32 regs/thread (block owns its (seq,hcol) slice);
//     cbuf + its memset deleted. Bias sums preloaded (thread's column fixed).
//   - x-phase GEMM issued BEFORE the barrier wait (overlaps sibling skew);
//     t=0 skips h-phase + barrier (h==0), h0 memset deleted.
// Wave = gate (16 hcols x 4 gates per block, 64 seqs); MFMA 16x16x32 bf16;
// epilogue (verified R2/R5/R6) exchanges gate tiles via LDS G, bf16 h ping-pong.

#define T_ 100
#define D_ 512
#define H_ 512
#define N_ 640
#define AS 136   // A-chunk LDS row stride in bf16 elems (128 data + 8 pad)
#define NSB 10   // seq-blocks (64 seqs each)
#define NGR 32   // hcol groups (16 cols each)

using short8  = __attribute__((ext_vector_type(8))) short;  // 8 bf16
using floatx4 = __attribute__((ext_vector_type(4))) float;  // MFMA C/D

__device__ __forceinline__ float sigmoidf_(float x) {
    return 1.0f / (1.0f + __expf(-x));
}

__device__ __forceinline__ unsigned short f2bf(float f) {  // RNE, finite inputs
    union { float f; unsigned int u; } v; v.f = f;
    unsigned int u = v.u;
    u += 0x7fffu + ((u >> 16) & 1u);
    return (unsigned short)(u >> 16);
}

__device__ __forceinline__ short8 cvt8(const float* __restrict__ p) {
    const float4 a = *(const float4*)p;
    const float4 b = *(const float4*)(p + 4);
    short8 r;
    r[0] = (short)f2bf(a.x); r[1] = (short)f2bf(a.y);
    r[2] = (short)f2bf(a.z); r[3] = (short)f2bf(a.w);
    r[4] = (short)f2bf(b.x); r[5] = (short)f2bf(b.y);
    r[6] = (short)f2bf(b.z); r[7] = (short)f2bf(b.w);
    return r;
}

// fp32 -> bf16, 8 elements/thread
__global__ __launch_bounds__(256) void cvt_bf16(const float* __restrict__ src,
                                                unsigned short* __restrict__ dst, int n) {
    const int i = (blockIdx.x * 256 + threadIdx.x) * 8;
    if (i < n) {
        const float4 a = *(const float4*)(src + i);
        const float4 b = *(const float4*)(src + i + 4);
        ushort4 o0, o1;
        o0.x = f2bf(a.x); o0.y = f2bf(a.y); o0.z = f2bf(a.z); o0.w = f2bf(a.w);
        o1.x = f2bf(b.x); o1.y = f2bf(b.y); o1.z = f2bf(b.z); o1.w = f2bf(b.w);
        *(ushort4*)(dst + i)     = o0;
        *(ushort4*)(dst + i + 4) = o1;
    }
}

template <bool XBF>
__global__ __launch_bounds__(256, 2) void lstm_persist(
    const void* __restrict__ xsrc,             // [N,T,D] bf16 (XBF) else fp32
    const __hip_bfloat16* __restrict__ Wih,    // [4H, D] bf16
    const __hip_bfloat16* __restrict__ Whh,    // [4H, H] bf16
    const float* __restrict__ bih,             // [4H]
    const float* __restrict__ bhh,             // [4H]
    __hip_bfloat16* __restrict__ h0,           // [N,H] bf16 ping
    __hip_bfloat16* __restrict__ h1,           // [N,H] bf16 pong
    float* __restrict__ out,                   // d_out fp32 [N,H]
    int* __restrict__ sync)                    // [T_][NSB] arrival counters (zeroed)
{
    __shared__ __hip_bfloat16 A[64 * AS];  // 17408 B
    __shared__ float G[4][64][16];         // 16384 B

    const int tid  = threadIdx.x;
    const int bid  = blockIdx.x;
    const int grp  = bid & 31;   // hcol-group; bid%8 = XCD (x/h tile L2 sharing)
    const int sb   = bid >> 5;   // seq-block 0..9 (consecutive bids share sb)
    const int gate = tid >> 6;
    const int lane = tid & 63;
    const int l15  = lane & 15;
    const int quad = lane >> 4;
    const int seq0 = sb * 64;
    const int hc0  = grp * 16;

    const int r = gate * H_ + hc0 + l15;  // W row (output gate-col) for this lane

    // ---- load this block's weight slice into registers, ONCE ----
    // wreg[phase][chunk][ki]: B-fragment, cols = chunk*128 + ki*32 + quad*8 +[0,8)
    short8 wreg[2][4][4];
    {
        const __hip_bfloat16* w0 = Wih + (size_t)r * 512 + quad * 8;
        const __hip_bfloat16* w1 = Whh + (size_t)r * 512 + quad * 8;
        #pragma unroll
        for (int c = 0; c < 4; ++c)
            #pragma unroll
            for (int k = 0; k < 4; ++k) {
                wreg[0][c][k] = *(const short8*)(w0 + c * 128 + k * 32);
                wreg[1][c][k] = *(const short8*)(w1 + c * 128 + k * 32);
            }
    }

    // ---- epilogue column is fixed for this thread: preload bias sums ----
    const int colj = hc0 + (tid & 15);
    const float bi = bih[0 * H_ + colj] + bhh[0 * H_ + colj];
    const float bf = bih[1 * H_ + colj] + bhh[1 * H_ + colj];
    const float bg = bih[2 * H_ + colj] + bhh[2 * H_ + colj];
    const float bo = bih[3 * H_ + colj] + bhh[3 * H_ + colj];

    // ---- c state in registers: this block exclusively owns its slice ----
    float creg[4] = {0.f, 0.f, 0.f, 0.f};

    const float*          af0 = XBF ? nullptr : (const float*)xsrc + (size_t)seq0 * T_ * D_;
    const __hip_bfloat16* ab0 = XBF ? (const __hip_bfloat16*)xsrc + (size_t)seq0 * T_ * D_ : nullptr;

    #pragma unroll 1
    for (int t = 0; t < T_; ++t) {
        const __hip_bfloat16* hp = (t & 1) ? h1 : h0;
        __hip_bfloat16*       hn = (t & 1) ? h0 : h1;

        floatx4 acc[4] = {};

        // ---- phase 0: x_t @ Wih^T (needs no h -> overlaps sibling skew) ----
        {
            const size_t astr = (size_t)T_ * D_;
            const size_t toff = (size_t)t * D_;
            #pragma unroll
            for (int c = 0; c < 4; ++c) {
                __syncthreads();
                #pragma unroll
                for (int u = 0; u < 4; ++u) {
                    const int slot = u * 256 + tid;
                    const int row  = slot >> 4;
                    const int c16  = slot & 15;
                    short8 v;
                    if (XBF) v = *(const short8*)(ab0 + row * astr + toff + c * 128 + c16 * 8);
                    else     v = cvt8(af0 + row * astr + toff + c * 128 + c16 * 8);
                    *(short8*)&A[row * AS + c16 * 8] = v;
                }
                __syncthreads();
                #pragma unroll
                for (int ki = 0; ki < 4; ++ki)
                    #pragma unroll
                    for (int mi = 0; mi < 4; ++mi) {
                        const short8 afrag =
                            *(const short8*)&A[(mi * 16 + l15) * AS + ki * 32 + quad * 8];
                        acc[mi] = __builtin_amdgcn_mfma_f32_16x16x32_bf16(afrag, wreg[0][c][ki],
                                                                          acc[mi], 0, 0, 0);
                    }
            }
        }

        // ---- wait for h(t-1) from the other 31 blocks of this sb-group ----
        if (t > 0) {
            if (tid == 0) {
                const int* sp = &sync[(t - 1) * NSB + sb];
                while (__hip_atomic_load(sp, __ATOMIC_RELAXED, __HIP_MEMORY_SCOPE_AGENT) < NGR)
                    __builtin_amdgcn_s_sleep(1);
            }
            __syncthreads();
            __threadfence();  // acquire: invalidate stale cache lines before hp reads

            // ---- phase 1: h_{t-1} @ Whh^T ----
            const __hip_bfloat16* ah = hp + (size_t)seq0 * H_;
            #pragma unroll
            for (int c = 0; c < 4; ++c) {
                __syncthreads();
                #pragma unroll
                for (int u = 0; u < 4; ++u) {
                    const int slot = u * 256 + tid;
                    const int row  = slot >> 4;
                    const int c16  = slot & 15;
                    *(short8*)&A[row * AS + c16 * 8] =
                        *(const short8*)(ah + row * H_ + c * 128 + c16 * 8);
                }
                __syncthreads();
                #pragma unroll
                for (int ki = 0; ki < 4; ++ki)
                    #pragma unroll
                    for (int mi = 0; mi < 4; ++mi) {
                        const short8 afrag =
                            *(const short8*)&A[(mi * 16 + l15) * AS + ki * 32 + quad * 8];
                        acc[mi] = __builtin_amdgcn_mfma_f32_16x16x32_bf16(afrag, wreg[1][c][ki],
                                                                          acc[mi], 0, 0, 0);
                    }
            }
        }

        // ---- epilogue: exchange gate tiles via LDS, fused cell update ----
        // C/D: col = lane&15 (hcol), row = quad*4 + reg (seq)
        #pragma unroll
        for (int mi = 0; mi < 4; ++mi)
            #pragma unroll
            for (int rg = 0; rg < 4; ++rg)
                G[gate][mi * 16 + quad * 4 + rg][l15] = acc[mi][rg];
        __syncthreads();

        #pragma unroll
        for (int i = 0; i < 4; ++i) {
            const int sl = (tid >> 4) + 16 * i;
            const int cc = tid & 15;
            const int n  = seq0 + sl;

            const float gi = sigmoidf_(G[0][sl][cc] + bi);
            const float gf = sigmoidf_(G[1][sl][cc] + bf);
            const float gg = tanhf(G[2][sl][cc] + bg);
            const float go = sigmoidf_(G[3][sl][cc] + bo);

            const float cn = gf * creg[i] + gi * gg;
            creg[i] = cn;
            const float hv = go * tanhf(cn);
            hn[(size_t)n * H_ + colj] = __float2bfloat16(hv);
            if (t == T_ - 1) out[(size_t)n * H_ + colj] = hv;
        }

        // ---- publish h(t): barrier drains all waves' stores, then release ----
        if (t < T_ - 1) {
            __syncthreads();  // s_waitcnt vmcnt(0) at barrier: block stores in L2
            if (tid == 0)
                __hip_atomic_fetch_add(&sync[t * NSB + sb], 1,
                                       __ATOMIC_RELEASE, __HIP_MEMORY_SCOPE_AGENT);
        }
    }
}

extern "C" void kernel_launch(void* const* d_in, const int* in_sizes, int n_in,
                              void* d_out, int out_size, void* d_ws, size_t ws_size,
                              hipStream_t stream) {
    const float* x    = (const float*)d_in[0];
    const float* Wihf = (const float*)d_in[1];
    const float* Whhf = (const float*)d_in[2];
    const float* bih  = (const float*)d_in[3];
    const float* bhh  = (const float*)d_in[4];

    const size_t nW = (size_t)4 * H_ * D_;   // 1,048,576
    const size_t nX = (size_t)N_ * T_ * D_;  // 32,768,000
    const size_t nH = (size_t)N_ * H_;       // 327,680

    // ws: Wb | Ub | h0 | h1 | sync | [xb]
    char* p = (char*)d_ws;
    __hip_bfloat16* Wb = (__hip_bfloat16*)p;  p += nW * 2;
    __hip_bfloat16* Ub = (__hip_bfloat16*)p;  p += nW * 2;
    __hip_bfloat16* h0 = (__hip_bfloat16*)p;  p += nH * 2;
    __hip_bfloat16* h1 = (__hip_bfloat16*)p;  p += nH * 2;
    int* syncbuf = (int*)p;                   p += 4096;  // 4000 B used, pad to 16B align
    const size_t need_xb = (size_t)(p - (char*)d_ws) + nX * 2;
    const bool use_xb = ws_size >= need_xb;
    __hip_bfloat16* xb = use_xb ? (__hip_bfloat16*)p : nullptr;

    cvt_bf16<<<(int)(nW / (256 * 8)), 256, 0, stream>>>(Wihf, (unsigned short*)Wb, (int)nW);
    cvt_bf16<<<(int)(nW / (256 * 8)), 256, 0, stream>>>(Whhf, (unsigned short*)Ub, (int)nW);
    if (use_xb)
        cvt_bf16<<<(int)(nX / (256 * 8)), 256, 0, stream>>>(x, (unsigned short*)xb, (int)nX);

    hipMemsetAsync(syncbuf, 0, (size_t)T_ * NSB * sizeof(int), stream);

    const int nblk = NSB * NGR;  // 320; sb = bid>>5 so consecutive bids share sb
    if (use_xb)
        lstm_persist<true><<<nblk, 256, 0, stream>>>(xb, Wb, Ub, bih, bhh, h0, h1,
                                                     (float*)d_out, syncbuf);
    else
        lstm_persist<false><<<nblk, 256, 0, stream>>>(x, Wb, Ub, bih, bhh, h0, h1,
                                                      (float*)d_out, syncbuf);
}

// Round 3
// 2124.716 us; speedup vs baseline: 2.3691x; 2.3691x over previous
//
#include <hip/hip_runtime.h>
#include <hip/hip_bf16.h>

// LSTM: N=640 seqs (B*Q fused), T=100, D=H=512. Inputs fp32; d_out fp32.
// R9 = R8 bugfixed. R8 hung: sync indexed [sb*32+t] with t<=98 -> slots up
// to 386 but only 320 zeroed -> garbage counters -> infinite spin. Fix:
//   - sync back to R7's proven [t*NSB+sb], all T_*NSB ints zeroed.
//   - LDS: no 64KB union edge; A staged in 2 K=256 chunks (32KB, XOR
//     swizzle byte^=(row&7)<<4 on 512B rows) + separate G = 50176 B total.
//     >=2 blocks/CU -> all 320 blocks co-resident (deadlock-safe, no coop).
//   - h publish: shfl_xor pair-pack -> 32-bit relaxed AGENT atomic stores
//     (write-through to LLC, sc0 sc1); h staging = 8B relaxed AGENT atomic
//     loads (read LLC, never-stale). NO fences -> no buffer_inv/wbl2 (the
//     R7 5034us regression). Counter protocol: stores, s_waitcnt vmcnt(0),
//     __syncthreads, tid0 relaxed add = release without L2 writeback.
//   Kept from R8: weights in 128 VGPRs (loaded once), c in 4 fp32 regs,
//   biases preloaded, x-GEMM issued before the spin-wait (overlaps sibling
//   skew), XCD-contiguous sb-groups (s=(bid&7)*40+bid>>3), t=0 skips
//   h-phase. Same accumulation order as R6/R7 -> same numerics.

#define T_ 100
#define D_ 512
#define H_ 512
#define N_ 640
#define NSB 10   // seq-blocks (64 seqs each)
#define NGR 32   // hcol groups (16 cols each)

using short8  = __attribute__((ext_vector_type(8))) short;  // 8 bf16
using floatx4 = __attribute__((ext_vector_type(4))) float;  // MFMA C/D

__device__ __forceinline__ float sigmoidf_(float x) {
    return 1.0f / (1.0f + __expf(-x));
}

__device__ __forceinline__ unsigned short f2bf(float f) {  // RNE, finite inputs
    union { float f; unsigned int u; } v; v.f = f;
    unsigned int u = v.u;
    u += 0x7fffu + ((u >> 16) & 1u);
    return (unsigned short)(u >> 16);
}

__device__ __forceinline__ short8 cvt8(const float* __restrict__ p) {
    const float4 a = *(const float4*)p;
    const float4 b = *(const float4*)(p + 4);
    short8 r;
    r[0] = (short)f2bf(a.x); r[1] = (short)f2bf(a.y);
    r[2] = (short)f2bf(a.z); r[3] = (short)f2bf(a.w);
    r[4] = (short)f2bf(b.x); r[5] = (short)f2bf(b.y);
    r[6] = (short)f2bf(b.z); r[7] = (short)f2bf(b.w);
    return r;
}

// fp32 -> bf16, 8 elements/thread
__global__ __launch_bounds__(256) void cvt_bf16(const float* __restrict__ src,
                                                unsigned short* __restrict__ dst, int n) {
    const int i = (blockIdx.x * 256 + threadIdx.x) * 8;
    if (i < n) {
        const float4 a = *(const float4*)(src + i);
        const float4 b = *(const float4*)(src + i + 4);
        ushort4 o0, o1;
        o0.x = f2bf(a.x); o0.y = f2bf(a.y); o0.z = f2bf(a.z); o0.w = f2bf(a.w);
        o1.x = f2bf(b.x); o1.y = f2bf(b.y); o1.z = f2bf(b.z); o1.w = f2bf(b.w);
        *(ushort4*)(dst + i)     = o0;
        *(ushort4*)(dst + i + 4) = o1;
    }
}

template <bool XBF>
__global__ __launch_bounds__(256, 2) void lstm_persist(
    const void* __restrict__ xsrc,             // [N,T,D] bf16 (XBF) else fp32
    const __hip_bfloat16* __restrict__ Wih,    // [4H, D] bf16
    const __hip_bfloat16* __restrict__ Whh,    // [4H, H] bf16
    const float* __restrict__ bih,             // [4H]
    const float* __restrict__ bhh,             // [4H]
    __hip_bfloat16* __restrict__ h0,           // [N,H] bf16 ping
    __hip_bfloat16* __restrict__ h1,           // [N,H] bf16 pong
    float* __restrict__ out,                   // d_out fp32 [N,H]
    int* __restrict__ sync)                    // [T_][NSB] arrival counters (zeroed)
{
    __shared__ unsigned char A[64 * 512];  // 64 rows x 256 bf16 (one K-half), swizzled
    __shared__ float G[4][64][17];         // gate exchange
    // total 50176 B -> >=2 blocks/CU

    const int tid = threadIdx.x;
    const int bid = blockIdx.x;
    // XCD-contiguous sb-groups: bid%8 = XCD (empirical round-robin; perf-only)
    const int s    = (bid & 7) * 40 + (bid >> 3);  // 0..319
    const int sb   = s >> 5;                       // 0..9
    const int grp  = s & 31;                       // 0..31
    const int gate = tid >> 6;
    const int lane = tid & 63;
    const int l15  = lane & 15;
    const int quad = lane >> 4;
    const int seq0 = sb * 64;
    const int hc0  = grp * 16;

    const int r = gate * H_ + hc0 + l15;  // W row (output gate-col) for this lane

    // ---- weight slice in registers, loaded ONCE (plain cached loads) ----
    short8 wreg[2][4][4];  // [phase][k-128chunk][ki]; cols chunk*128+ki*32+quad*8
    {
        const __hip_bfloat16* w0 = Wih + (size_t)r * 512 + quad * 8;
        const __hip_bfloat16* w1 = Whh + (size_t)r * 512 + quad * 8;
        #pragma unroll
        for (int c = 0; c < 4; ++c)
            #pragma unroll
            for (int k = 0; k < 4; ++k) {
                wreg[0][c][k] = *(const short8*)(w0 + c * 128 + k * 32);
                wreg[1][c][k] = *(const short8*)(w1 + c * 128 + k * 32);
            }
    }

    // ---- fixed epilogue column: preload bias sums ----
    const int colj = hc0 + (tid & 15);
    const float bi = bih[0 * H_ + colj] + bhh[0 * H_ + colj];
    const float bf = bih[1 * H_ + colj] + bhh[1 * H_ + colj];
    const float bg = bih[2 * H_ + colj] + bhh[2 * H_ + colj];
    const float bo = bih[3 * H_ + colj] + bhh[3 * H_ + colj];

    float creg[4] = {0.f, 0.f, 0.f, 0.f};  // c state, block-exclusive

    const float*          af0 = XBF ? nullptr : (const float*)xsrc + (size_t)seq0 * T_ * D_;
    const __hip_bfloat16* ab0 = XBF ? (const __hip_bfloat16*)xsrc + (size_t)seq0 * T_ * D_ : nullptr;

    #pragma unroll 1
    for (int t = 0; t < T_; ++t) {
        const __hip_bfloat16* hp = (t & 1) ? h1 : h0;
        __hip_bfloat16*       hn = (t & 1) ? h0 : h1;

        floatx4 acc[4] = {};

        // ================= phase 0: x_t @ Wih^T (no h needed) =================
        {
            const size_t astr = (size_t)T_ * D_;
            const size_t toff = (size_t)t * D_;
            #pragma unroll
            for (int half = 0; half < 2; ++half) {
                const int kc = half * 256;
                __syncthreads();  // previous A readers done
                #pragma unroll
                for (int u = 0; u < 8; ++u) {
                    const int slot = u * 256 + tid;   // 2048 x 16B slots
                    const int row  = slot >> 5;
                    const int c16  = slot & 31;
                    short8 v;
                    if (XBF) v = *(const short8*)(ab0 + row * astr + toff + kc + c16 * 8);
                    else     v = cvt8(af0 + row * astr + toff + kc + c16 * 8);
                    *(short8*)(A + row * 512 + ((c16 << 4) ^ ((row & 7) << 4))) = v;
                }
                __syncthreads();
                #pragma unroll
                for (int kk = 0; kk < 8; ++kk) {   // 8 x K=32
                    const short8 bfrag = wreg[0][half * 2 + (kk >> 2)][kk & 3];
                    #pragma unroll
                    for (int mi = 0; mi < 4; ++mi) {
                        const int row = mi * 16 + l15;
                        const short8 afrag = *(const short8*)(
                            A + row * 512 + (((kk << 6) + (quad << 4)) ^ ((row & 7) << 4)));
                        acc[mi] = __builtin_amdgcn_mfma_f32_16x16x32_bf16(afrag, bfrag,
                                                                          acc[mi], 0, 0, 0);
                    }
                }
            }
        }

        // ================= phase 1: h_{t-1} @ Whh^T =================
        if (t > 0) {
            // wait for h(t-1) from this sb-group's 32 blocks
            if (tid == 0) {
                const int* sp = &sync[(t - 1) * NSB + sb];
                while (__hip_atomic_load(sp, __ATOMIC_RELAXED, __HIP_MEMORY_SCOPE_AGENT) < NGR)
                    __builtin_amdgcn_s_sleep(1);
            }
            __syncthreads();  // h ready; also x-GEMM A readers done

            const unsigned long long* hp8 =
                (const unsigned long long*)(hp + (size_t)seq0 * H_);
            #pragma unroll
            for (int half = 0; half < 2; ++half) {
                const int kc8 = half * 64;        // 8B units within row (256 bf16)
                if (half) __syncthreads();        // previous-half A readers done
                #pragma unroll
                for (int u = 0; u < 16; ++u) {
                    const int slot = u * 256 + tid;   // 4096 x 8B slots
                    const int row  = slot >> 6;
                    const int c8   = slot & 63;
                    const unsigned long long v = __hip_atomic_load(
                        hp8 + row * 128 + kc8 + c8, __ATOMIC_RELAXED,
                        __HIP_MEMORY_SCOPE_AGENT);
                    *(unsigned long long*)(A + row * 512 +
                                           ((c8 << 3) ^ ((row & 7) << 4))) = v;
                }
                __syncthreads();
                #pragma unroll
                for (int kk = 0; kk < 8; ++kk) {
                    const short8 bfrag = wreg[1][half * 2 + (kk >> 2)][kk & 3];
                    #pragma unroll
                    for (int mi = 0; mi < 4; ++mi) {
                        const int row = mi * 16 + l15;
                        const short8 afrag = *(const short8*)(
                            A + row * 512 + (((kk << 6) + (quad << 4)) ^ ((row & 7) << 4)));
                        acc[mi] = __builtin_amdgcn_mfma_f32_16x16x32_bf16(afrag, bfrag,
                                                                          acc[mi], 0, 0, 0);
                    }
                }
            }
        }

        // ================= epilogue =================
        // C/D: col = lane&15 (hcol), row = quad*4 + reg (seq). G separate from A.
        #pragma unroll
        for (int mi = 0; mi < 4; ++mi)
            #pragma unroll
            for (int rg = 0; rg < 4; ++rg)
                G[gate][mi * 16 + quad * 4 + rg][l15] = acc[mi][rg];
        __syncthreads();

        #pragma unroll
        for (int i = 0; i < 4; ++i) {
            const int sl = (tid >> 4) + 16 * i;
            const int cc = tid & 15;
            const int n  = seq0 + sl;

            const float gi = sigmoidf_(G[0][sl][cc] + bi);
            const float gf = sigmoidf_(G[1][sl][cc] + bf);
            const float gg = tanhf(G[2][sl][cc] + bg);
            const float go = sigmoidf_(G[3][sl][cc] + bo);

            const float cn = gf * creg[i] + gi * gg;
            creg[i] = cn;
            const float hv = go * tanhf(cn);

            if (t < T_ - 1) {
                // pair lanes (tid, tid^1) hold cols (cc, cc^1): pack to one
                // 32-bit relaxed AGENT store (write-through to LLC, no fence)
                const unsigned int hb    = f2bf(hv);
                const unsigned int other = __shfl_xor((int)hb, 1, 64);
                if ((tid & 1) == 0) {
                    unsigned int packed = hb | (other << 16);
                    __hip_atomic_store(
                        (unsigned int*)((unsigned short*)hn + (size_t)n * H_ + colj),
                        packed, __ATOMIC_RELAXED, __HIP_MEMORY_SCOPE_AGENT);
                }
            } else {
                out[(size_t)n * H_ + colj] = hv;  // kernel-end release covers d_out
            }
        }

        // ---- publish h(t): drain stores, block-barrier, then counted add ----
        if (t < T_ - 1) {
            asm volatile("s_waitcnt vmcnt(0)" ::: "memory");  // h stores at LLC
            __syncthreads();                                  // whole block drained
            if (tid == 0)
                __hip_atomic_fetch_add(&sync[t * NSB + sb], 1,
                                       __ATOMIC_RELAXED, __HIP_MEMORY_SCOPE_AGENT);
        }
    }
}

extern "C" void kernel_launch(void* const* d_in, const int* in_sizes, int n_in,
                              void* d_out, int out_size, void* d_ws, size_t ws_size,
                              hipStream_t stream) {
    const float* x    = (const float*)d_in[0];
    const float* Wihf = (const float*)d_in[1];
    const float* Whhf = (const float*)d_in[2];
    const float* bih  = (const float*)d_in[3];
    const float* bhh  = (const float*)d_in[4];

    const size_t nW = (size_t)4 * H_ * D_;   // 1,048,576
    const size_t nX = (size_t)N_ * T_ * D_;  // 32,768,000
    const size_t nH = (size_t)N_ * H_;       // 327,680

    // ws: Wb | Ub | h0 | h1 | sync | [xb]
    char* p = (char*)d_ws;
    __hip_bfloat16* Wb = (__hip_bfloat16*)p;  p += nW * 2;
    __hip_bfloat16* Ub = (__hip_bfloat16*)p;  p += nW * 2;
    __hip_bfloat16* h0 = (__hip_bfloat16*)p;  p += nH * 2;
    __hip_bfloat16* h1 = (__hip_bfloat16*)p;  p += nH * 2;
    int* syncbuf = (int*)p;                   p += 4096;  // [T_][NSB] = 1000 ints
    const size_t need_xb = (size_t)(p - (char*)d_ws) + nX * 2;
    const bool use_xb = ws_size >= need_xb;
    __hip_bfloat16* xb = use_xb ? (__hip_bfloat16*)p : nullptr;

    cvt_bf16<<<(int)(nW / (256 * 8)), 256, 0, stream>>>(Wihf, (unsigned short*)Wb, (int)nW);
    cvt_bf16<<<(int)(nW / (256 * 8)), 256, 0, stream>>>(Whhf, (unsigned short*)Ub, (int)nW);
    if (use_xb)
        cvt_bf16<<<(int)(nX / (256 * 8)), 256, 0, stream>>>(x, (unsigned short*)xb, (int)nX);

    hipMemsetAsync(syncbuf, 0, (size_t)T_ * NSB * sizeof(int), stream);

    const int nblk = NSB * NGR;  // 320; all co-resident at >=2 blocks/CU capacity
    if (use_xb)
        lstm_persist<true><<<nblk, 256, 0, stream>>>(xb, Wb, Ub, bih, bhh, h0, h1,
                                                     (float*)d_out, syncbuf);
    else
        lstm_persist<false><<<nblk, 256, 0, stream>>>(x, Wb, Ub, bih, bhh, h0, h1,
                                                      (float*)d_out, syncbuf);
}